// Round 3
// baseline (860.937 us; speedup 1.0000x reference)
//
#include <hip/hip_runtime.h>
#include <hip/hip_bf16.h>

#define HD 512      // d_model
#define NST 64      // d_state
#define NLAY 6
#define LSEQ 784
#define BB 64       // batch
#define TOFF 800    // KAS copy0: pos t holds K[TOFF - t]; t in [17,800] real, else 0
#define LPADROWS 800  // padded L (25 tiles of 32); pad rows killed by zero-K
#define KROW 850    // u16 stride of one shifted kernel copy (2 copies per (i,h))

typedef unsigned short u16;
typedef short s8v __attribute__((ext_vector_type(8)));   // 8 bf16 (4 VGPR)
typedef float f16v __attribute__((ext_vector_type(16))); // 32x32 MFMA acc
typedef u16  u8h __attribute__((ext_vector_type(8)));    // ushort8 (16B)

// fp32 -> bf16 bits, round-to-nearest-even
__device__ __forceinline__ unsigned f2b(float f)
{
    unsigned u = __builtin_bit_cast(unsigned, f);
    return (u + 0x7FFFu + ((u >> 16) & 1u)) >> 16;
}
__device__ __forceinline__ float b2f16(u16 v)
{
    unsigned u = ((unsigned)v) << 16;
    return __builtin_bit_cast(float, u);
}
// pack 2 fp32 -> 2 bf16 (RNE), lo|hi<<16 — single HW instruction on gfx950
__device__ __forceinline__ unsigned pkbf(float lo, float hi)
{
    unsigned r;
    asm("v_cvt_pk_bf16_f32 %0, %1, %2" : "=v"(r) : "v"(lo), "v"(hi));
    return r;
}

// ---------------------------------------------------------------------------
// Per (layer,h,n): lambda = exp(dt*A), dtA, 2*Cd. Layout [i][h][n].
// ---------------------------------------------------------------------------
__global__ void precompute_k(const float* __restrict__ log_dt,
                             const float* __restrict__ log_A_real,
                             const float* __restrict__ A_imag,
                             const float* __restrict__ C_re,
                             const float* __restrict__ C_im,
                             float* __restrict__ lamr, float* __restrict__ lami,
                             float* __restrict__ dtr,  float* __restrict__ dti,
                             float* __restrict__ c2r,  float* __restrict__ c2i)
{
    int t = blockIdx.x * 256 + threadIdx.x;
    if (t >= NLAY * HD * NST) return;
    int ih = t >> 6;                       // i*HD + h
    float dt  = expf(log_dt[ih]);
    float are = -expf(log_A_real[t]);
    float aim = A_imag[t];
    float dr = are * dt, di = aim * dt;
    float er = expf(dr);
    float sn, cs; __sincosf(di, &sn, &cs);
    float lr = er * cs, li = er * sn;      // lambda
    float e1r = lr - 1.0f, e1i = li;
    float den = are * are + aim * aim;
    float qr = (e1r * are + e1i * aim) / den;
    float qi = (e1i * are - e1r * aim) / den;
    float crv = C_re[t], civ = C_im[t];
    lamr[t] = lr; lami[t] = li; dtr[t] = dr; dti[t] = di;
    c2r[t] = 2.0f * (crv * qr - civ * qi);
    c2i[t] = 2.0f * (crv * qi + civ * qr);
}

// ---------------------------------------------------------------------------
// Build KAS[i][h]: TWO shifted copies (850 u16 each) of the reversed,
// zero-padded conv kernel.  Copy s holds K-rev at position s + t, so a read
// whose u16 index is even can pick copy (n2&1) and stay dword-aligned.
// ---------------------------------------------------------------------------
__global__ void kq_k(const float* __restrict__ lamr, const float* __restrict__ lami,
                     const float* __restrict__ dtr,  const float* __restrict__ dti,
                     const float* __restrict__ c2r,  const float* __restrict__ c2i,
                     u16* __restrict__ KAS)
{
    int t = blockIdx.x * 256 + threadIdx.x;   // < 6*512*49
    int dc = t % 49;
    int ih = t / 49;                          // i*HD + h
    int d0 = dc * 16;
    float acc[16];
#pragma unroll
    for (int k = 0; k < 16; k++) acc[k] = 0.f;
    int base = ih * 64;
    for (int n = 0; n < 64; n++) {
        float lr = lamr[base + n], li = lami[base + n];
        float dr = dtr[base + n],  di = dti[base + n];
        float cr = c2r[base + n],  ci = c2i[base + n];
        float e = __expf(dr * (float)d0);
        float sn, cs; __sincosf(di * (float)d0, &sn, &cs);
        float pr = e * cs, pi = e * sn;       // lam^d0
#pragma unroll
        for (int k = 0; k < 16; k++) {
            acc[k] = fmaf(cr, pr, fmaf(-ci, pi, acc[k]));
            float nr = pr * lr - pi * li;
            pi = fmaf(pr, li, pi * lr);
            pr = nr;
        }
    }
    u16* r0p = KAS + (size_t)ih * 2 * KROW;   // copy 0
    u16* r1p = r0p + KROW;                    // copy 1 (shift +1)
#pragma unroll
    for (int k = 0; k < 16; k++) {
        u16 vb = (u16)f2b(acc[k]);
        int tt = TOFF - (d0 + k);
        r0p[tt] = vb;
        r1p[1 + tt] = vb;
    }
    if (dc == 0) {
        for (int z = TOFF + 1; z < KROW; z++) r0p[z] = 0;       // 801..849
        for (int z = TOFF + 2; z < KROW; z++) r1p[z] = 0;       // 802..849
        r1p[0] = 0;
    }
    if (dc == 48) {
        for (int z = 0; z < TOFF - 783; z++) { r0p[z] = 0; r1p[1 + z] = 0; }
    }
}

// ---------------------------------------------------------------------------
// Transpose x[b][l] -> xT[l][b] (200 KB, L2-resident; cost ~2 us)
// ---------------------------------------------------------------------------
__global__ void xt_k(const float* __restrict__ x, float* __restrict__ xT)
{
    int t = blockIdx.x * 256 + threadIdx.x;   // < 784*64
    int l = t >> 6, b = t & 63;
    xT[t] = x[b * LSEQ + l];
}

// ---------------------------------------------------------------------------
// Encoder: thread = (l, h, b-oct).  Extended to LPADROWS: pad rows get ZEROS
// (so layer-0 staging never ingests uninitialized ws memory / NaNs).
// ---------------------------------------------------------------------------
__global__ void encoder_k(const float* __restrict__ xT, const float* __restrict__ ew,
                          const float* __restrict__ eb, u16* __restrict__ Vb)
{
    int g = blockIdx.x * 256 + threadIdx.x;   // < 800*512*8
    int bo = g & 7;
    int h  = (g >> 3) & 511;
    int l  = g >> 12;
    uint4* dst = (uint4*)&Vb[((size_t)l * HD + h) * BB + 8 * bo];
    if (l >= LSEQ) { *dst = (uint4){0, 0, 0, 0}; return; }
    const float4* xp = (const float4*)&xT[l * BB + 8 * bo];
    float4 a0 = xp[0], a1 = xp[1];
    float w = ew[h], bb = eb[h];
    unsigned p0 = f2b(fmaf(a0.x, w, bb)) | (f2b(fmaf(a0.y, w, bb)) << 16);
    unsigned p1 = f2b(fmaf(a0.z, w, bb)) | (f2b(fmaf(a0.w, w, bb)) << 16);
    unsigned p2 = f2b(fmaf(a1.x, w, bb)) | (f2b(fmaf(a1.y, w, bb)) << 16);
    unsigned p3 = f2b(fmaf(a1.z, w, bb)) | (f2b(fmaf(a1.w, w, bb)) << 16);
    *dst = (uint4){p0, p1, p2, p3};
}

// ---------------------------------------------------------------------------
// Per-(l,b) LayerNorm stats of pre-LN stream P: M[l][b] = {mu, rs}.
// Pad rows (l >= LSEQ) get identity stats {0,1} so fused-LN stays finite.
// ---------------------------------------------------------------------------
__global__ __launch_bounds__(256)
void stats_k(const u16* __restrict__ P, float2* __restrict__ M)
{
    __shared__ float redS[32][65], redQ[32][65];
    const int thr = threadIdx.x;
    const size_t l = blockIdx.x;
    if (l >= LSEQ) {
        if (thr < BB) M[l * BB + thr] = make_float2(0.f, 1.f);
        return;
    }
    const int bo = thr & 7;           // b = 8*bo + i
    const int ho = thr >> 3;          // h = 16*ho + k
    const u16* sp = &P[(l * HD + (size_t)ho * 16) * BB + 8 * bo];
    float s[8] = {0, 0, 0, 0, 0, 0, 0, 0};
    float q[8] = {0, 0, 0, 0, 0, 0, 0, 0};
#pragma unroll
    for (int k = 0; k < 16; k++) {
        u8h r = *(const u8h*)(sp + (size_t)k * BB);
#pragma unroll
        for (int i = 0; i < 8; i++) {
            float x = b2f16(r[i]);
            s[i] += x;
            q[i] = fmaf(x, x, q[i]);
        }
    }
#pragma unroll
    for (int i = 0; i < 8; i++) { redS[ho][8 * bo + i] = s[i]; redQ[ho][8 * bo + i] = q[i]; }
    __syncthreads();
    if (thr < 64) {
        float ts = 0.f, tq = 0.f;
#pragma unroll
        for (int g = 0; g < 32; g++) { ts += redS[g][thr]; tq += redQ[g][thr]; }
        float mu = ts * (1.0f / HD);
        float rs = rsqrtf(tq * (1.0f / HD) - mu * mu + 1e-5f);
        M[l * BB + thr] = make_float2(mu, rs);
    }
}

// ---------------------------------------------------------------------------
// STREAMING MFMA causal-Toeplitz conv.  One block per h (512 blocks, 128 thr,
// 1 block/CU).  The whole 800-row normalized input stream for this h lives in
// LDS; the Toeplitz kernel A-fragments (25 deltas x 2 K-chunks) live in
// registers, loaded once from the pre-shifted global KAS.  Per input tile:
// 2 LDS B-reads feed up to 10 MFMAs.  6 barriers per block total.
// LDS layout: dword(t,b,jj) at (t*64+b)*20 + (jj ^ (((b>>3)&3)<<2));
// jj = j-row-pair index 0..15 of 32-row tile t (stride 20 keeps b128 reads
// 16B-aligned; the XOR spreads the 4-lane bank groups).
// ---------------------------------------------------------------------------
template<int FLN>
__global__ __launch_bounds__(128, 1)
void sconv_k(const u16* __restrict__ Vb, u16* __restrict__ V2,
             const u16* __restrict__ KAS, const float* __restrict__ Dvec,
             const float2* __restrict__ M,
             const float* __restrict__ gp, const float* __restrict__ bp)
{
    __shared__ __align__(16) unsigned SB[25 * 64 * 20];   // 128,000 B

    const int thr = threadIdx.x;
    const int h   = blockIdx.x;
    const int lane = thr & 63;
    const int w   = thr >> 6;          // b-half for MFMA/epilogue phase
    const int n2  = lane & 31;
    const int qp  = lane >> 5;

    const float gh = FLN ? gp[h] : 0.f;
    const float bh = FLN ? bp[h] : 0.f;
    const float dcoef = 1.0f + Dvec[h];

    // ---- A-fragments: 25 deltas x 2 chunks, from global KAS into regs ----
    s8v afr[25][2];
    {
        const int sA = n2 & 1;
        const u16* kb = KAS + ((size_t)h * 2 + sA) * KROW + sA
                        + TOFF - n2 + 8 * qp;
#pragma unroll
        for (int dd = 0; dd < 25; dd++)
#pragma unroll
            for (int ch = 0; ch < 2; ch++) {
                const u16* kp = kb - 32 * dd + 16 * ch;   // even u16 index
                union { unsigned uu[4]; s8v v; } af;
#pragma unroll
                for (int q = 0; q < 4; q++)
                    af.uu[q] = *(const unsigned*)(kp + 2 * q);
                afr[dd][ch] = af.v;
            }
    }

    // ---- staging: 160 rows of group g0 -> LDS tiles 5*g0..5*g0+4 ----
    auto STAGE = [&](int g0) {
#pragma unroll
        for (int j5 = 0; j5 < 5; j5++) {
            int u  = thr + 128 * j5;      // 0..639
            int rp = u >> 3;              // row-pair 0..79
            int sg = u & 7;               // b-seg (8 cols)
            int r0 = 160 * g0 + 2 * rp;
            const u16* p = &Vb[((size_t)r0 * HD + h) * BB + 8 * sg];
            u8h ra = *(const u8h*)p;
            u8h rb = *(const u8h*)(p + (size_t)HD * BB);
            unsigned ov[8];
            if (FLN) {
                const float4* m0 = (const float4*)&M[(size_t)r0 * BB + 8 * sg];
                const float4* m1 = (const float4*)&M[(size_t)(r0 + 1) * BB + 8 * sg];
#pragma unroll
                for (int i = 0; i < 4; i++) {
                    float4 ma = m0[i], mb = m1[i];   // (mu,rs,mu,rs) b-pair
                    float A0 = ma.y * gh, C0 = fmaf(-ma.x, A0, bh);
                    float A1 = ma.w * gh, C1 = fmaf(-ma.z, A1, bh);
                    float B0 = mb.y * gh, D0 = fmaf(-mb.x, B0, bh);
                    float B1 = mb.w * gh, D1 = fmaf(-mb.z, B1, bh);
                    float x0 = fmaf(b2f16(ra[2 * i]),     A0, C0);
                    float x1 = fmaf(b2f16(ra[2 * i + 1]), A1, C1);
                    float y0 = fmaf(b2f16(rb[2 * i]),     B0, D0);
                    float y1 = fmaf(b2f16(rb[2 * i + 1]), B1, D1);
                    ov[2 * i]     = pkbf(x0, y0);
                    ov[2 * i + 1] = pkbf(x1, y1);
                }
            } else {
#pragma unroll
                for (int i = 0; i < 8; i++)
                    ov[i] = (unsigned)ra[i] | ((unsigned)rb[i] << 16);
            }
            int tt = 5 * g0 + (rp >> 4);
            int jj = rp & 15;
            unsigned* dst = &SB[(tt * 64 + 8 * sg) * 20 + (jj ^ ((sg & 3) << 2))];
#pragma unroll
            for (int k = 0; k < 8; k++) dst[k * 20] = ov[k];
        }
    };

    const int bcol = 32 * w + n2;
    const int swz  = ((bcol >> 3) & 3) << 2;
    const unsigned* bb0 = &SB[bcol * 20 + ((4 * qp) ^ swz)];
    const unsigned* bb1 = &SB[bcol * 20 + ((8 + 4 * qp) ^ swz)];

    STAGE(0);
    __syncthreads();

#pragma unroll
    for (int g = 0; g < 5; g++) {
        f16v acc[5];
#pragma unroll
        for (int i = 0; i < 5; i++)
#pragma unroll
            for (int r = 0; r < 16; r++) acc[i][r] = 0.f;

        // ---- t-loop: input tiles 0..5g+4, A from regs, B from LDS ----
#pragma unroll
        for (int t = 0; t < 25; t++) {
            if (t <= 5 * g + 4) {
                s8v bv0 = *(const s8v*)__builtin_assume_aligned(bb0 + t * 1280, 16);
                s8v bv1 = *(const s8v*)__builtin_assume_aligned(bb1 + t * 1280, 16);
#pragma unroll
                for (int Ti = 0; Ti < 5; Ti++) {
                    if (5 * g + Ti >= t) {
                        acc[Ti] = __builtin_amdgcn_mfma_f32_32x32x16_bf16(
                            afr[5 * g + Ti - t][0], bv0, acc[Ti], 0, 0, 0);
                        acc[Ti] = __builtin_amdgcn_mfma_f32_32x32x16_bf16(
                            afr[5 * g + Ti - t][1], bv1, acc[Ti], 0, 0, 0);
                    }
                }
            }
        }

        // ---- epilogue: V2 = bf16(y + (1+D)*u), u re-read from LDS ----
#pragma unroll
        for (int Ti = 0; Ti < 5; Ti++) {
            const int T = 5 * g + Ti;
#pragma unroll
            for (int k = 0; k < 4; k++) {
                int jjE = (2 * qp + 4 * k) ^ swz;    // even: b64-aligned
                const uint2 dw = *(const uint2*)__builtin_assume_aligned(
                    &SB[(T * 64 + bcol) * 20 + jjE], 8);
                float u0 = b2f16((u16)(dw.x & 0xffff));
                float u1 = b2f16((u16)(dw.x >> 16));
                float u2 = b2f16((u16)(dw.y & 0xffff));
                float u3 = b2f16((u16)(dw.y >> 16));
                int l = 32 * T + 8 * k + 4 * qp;
                size_t a = ((size_t)l * HD + h) * BB + bcol;
                V2[a]                       = (u16)f2b(fmaf(dcoef, u0, acc[Ti][4 * k + 0]));
                V2[a + (size_t)HD * BB]     = (u16)f2b(fmaf(dcoef, u1, acc[Ti][4 * k + 1]));
                V2[a + (size_t)2 * HD * BB] = (u16)f2b(fmaf(dcoef, u2, acc[Ti][4 * k + 2]));
                V2[a + (size_t)3 * HD * BB] = (u16)f2b(fmaf(dcoef, u3, acc[Ti][4 * k + 3]));
            }
        }

        if (g < 4) STAGE(g + 1);
        __syncthreads();
    }
}

// ---------------------------------------------------------------------------
// Fused double-LN tail: u6 = LN5(P5) (per-(l,b) stats in M, per-h g5/b5),
// then final LN over h of u6, write bf16. In-place safe (block owns its l).
// ---------------------------------------------------------------------------
__global__ __launch_bounds__(512)
void lnT2_k(const u16* __restrict__ src, u16* __restrict__ dst,
            const float2* __restrict__ M,
            const float* __restrict__ g5p, const float* __restrict__ b5p,
            const float* __restrict__ gp, const float* __restrict__ bp)
{
    __shared__ float redS[64][65], redQ[64][65];
    __shared__ float mus[64], rss[64];
    __shared__ float gs[512], bs[512];
    const int thr = threadIdx.x;
    const int bo = thr & 7;           // b = 8*bo + i
    const int hg = thr >> 3;          // h = 8*hg + k
    const size_t l = blockIdx.x;
    gs[thr] = gp[thr]; bs[thr] = bp[thr];

    const float4* mp = (const float4*)&M[l * BB + 8 * bo];
    float4 m0 = mp[0], m1 = mp[1], m2 = mp[2], m3 = mp[3];
    float mu5[8] = {m0.x, m0.z, m1.x, m1.z, m2.x, m2.z, m3.x, m3.z};
    float rs5[8] = {m0.y, m0.w, m1.y, m1.w, m2.y, m2.w, m3.y, m3.w};

    const u16* sp = &src[(l * HD + (size_t)hg * 8) * BB + 8 * bo];
    float v[64];                       // v[k*8+i]
    float s[8] = {0, 0, 0, 0, 0, 0, 0, 0};
    float q[8] = {0, 0, 0, 0, 0, 0, 0, 0};
#pragma unroll
    for (int k = 0; k < 8; k++) {
        u8h r = *(const u8h*)(sp + (size_t)k * BB);
        float g5 = g5p[hg * 8 + k], b5 = b5p[hg * 8 + k];
#pragma unroll
        for (int i = 0; i < 8; i++) {
            float x = fmaf(b2f16(r[i]) - mu5[i], rs5[i] * g5, b5);
            v[k * 8 + i] = x;
            s[i] += x;
            q[i] = fmaf(x, x, q[i]);
        }
    }
#pragma unroll
    for (int i = 0; i < 8; i++) { redS[hg][8 * bo + i] = s[i]; redQ[hg][8 * bo + i] = q[i]; }
    __syncthreads();
    if (thr < 64) {
        float ts = 0.f, tq = 0.f;
#pragma unroll
        for (int g = 0; g < 64; g++) { ts += redS[g][thr]; tq += redQ[g][thr]; }
        float mu = ts * (1.0f / HD);
        mus[thr] = mu;
        rss[thr] = rsqrtf(tq * (1.0f / HD) - mu * mu + 1e-5f);
    }
    __syncthreads();
    float mu[8], rs[8];
#pragma unroll
    for (int i = 0; i < 8; i++) { mu[i] = mus[8 * bo + i]; rs[i] = rss[8 * bo + i]; }
    u16* dp = &dst[(l * HD + (size_t)hg * 8) * BB + 8 * bo];
#pragma unroll
    for (int k = 0; k < 8; k++) {
        float g = gs[hg * 8 + k], bb = bs[hg * 8 + k];
        u8h wv;
#pragma unroll
        for (int i = 0; i < 8; i++)
            wv[i] = (u16)f2b(fmaf((v[k * 8 + i] - mu[i]) * rs[i], g, bb));
        *(u8h*)(dp + (size_t)k * BB) = wv;
    }
}

// ---------------------------------------------------------------------------
// Mean-pool over l from bf16 Vb: PO[h*64+b] = mean_l Vb[l][h][b].
// ---------------------------------------------------------------------------
__global__ void pool_k(const u16* __restrict__ Vb, float* __restrict__ PO)
{
    __shared__ float red[4][64];
    int h = blockIdx.x;
    int b = threadIdx.x & 63;
    int lg = threadIdx.x >> 6;               // 0..3
    const u16* p = &Vb[(size_t)h * BB + b];
    float s = 0.f;
    for (int l = lg; l < LSEQ; l += 4) s += b2f16(p[(size_t)l * HD * BB]);
    red[lg][b] = s;
    __syncthreads();
    if (threadIdx.x < 64) {
        float t = red[0][b] + red[1][b] + red[2][b] + red[3][b];
        PO[h * BB + b] = t * (1.0f / LSEQ);
    }
}

// ---------------------------------------------------------------------------
// Decoder: out[b,c] = PO[:,b] . dec_w[:,c] + dec_b[c]
// ---------------------------------------------------------------------------
__global__ void dec_k(const float* __restrict__ PO, const float* __restrict__ w,
                      const float* __restrict__ bias, float* __restrict__ out)
{
    int t = blockIdx.x * 256 + threadIdx.x;
    if (t >= BB * 10) return;
    int cc = t % 10, b = t / 10;
    float acc = bias[cc];
    for (int hh = 0; hh < HD; hh++)
        acc = fmaf(PO[hh * BB + b], w[hh * 10 + cc], acc);
    out[t] = acc;
}

// ---------------------------------------------------------------------------
extern "C" void kernel_launch(void* const* d_in, const int* in_sizes, int n_in,
                              void* d_out, int out_size, void* d_ws, size_t ws_size,
                              hipStream_t stream)
{
    const float* x   = (const float*)d_in[0];
    const float* ew  = (const float*)d_in[1];
    const float* eb  = (const float*)d_in[2];
    const float* ldt = (const float*)d_in[3];
    const float* lar = (const float*)d_in[4];
    const float* aim = (const float*)d_in[5];
    const float* cre = (const float*)d_in[6];
    const float* cim = (const float*)d_in[7];
    const float* Dp  = (const float*)d_in[8];
    const float* lng = (const float*)d_in[9];
    const float* lnb = (const float*)d_in[10];
    const float* fng = (const float*)d_in[11];
    const float* fnb = (const float*)d_in[12];
    const float* dw  = (const float*)d_in[13];
    const float* db  = (const float*)d_in[14];
    float* out = (float*)d_out;

    const size_t SZB = (size_t)BB * LPADROWS * HD;   // 26,214,400 u16 slots
    const size_t PP  = (size_t)NLAY * HD * NST;      // 196,608
    u16*   Vb  = (u16*)d_ws;                // bf16 stream buffer A [l][h][b]
    u16*   V2  = Vb + SZB;                  // bf16 stream buffer B
    float* PAR = (float*)(V2 + SZB);
    float* lamr = PAR,        * lami = PAR + PP;
    float* dtr  = PAR + 2*PP, * dti  = PAR + 3*PP;
    float* c2r  = PAR + 4*PP, * c2i  = PAR + 5*PP;
    u16* KAS = (u16*)(PAR + 6 * PP);                 // 6*512*2*850 u16 = 10.4 MB
    float* PO = (float*)(KAS + (size_t)NLAY * HD * 2 * KROW);
    float* xT = PO + BB * HD;                        // 784*64 fp32
    // M (LN stats, 800*64 float2 = 400KB) aliases PAR: PAR only feeds kq_k,
    // which completes before the first stats_k writes M.
    float2* M = (float2*)PAR;
    // total ~120 MB

    precompute_k<<<(NLAY * HD * NST + 255) / 256, 256, 0, stream>>>(
        ldt, lar, aim, cre, cim, lamr, lami, dtr, dti, c2r, c2i);
    kq_k<<<(NLAY * HD * 49) / 256, 256, 0, stream>>>(
        lamr, lami, dtr, dti, c2r, c2i, KAS);
    xt_k<<<(LSEQ * BB) / 256, 256, 0, stream>>>(x, xT);
    encoder_k<<<(LPADROWS * HD * 8) / 256, 256, 0, stream>>>(xT, ew, eb, Vb);

    // layer 0: raw input (no fused LN), P0 -> V2
    sconv_k<0><<<HD, 128, 0, stream>>>(Vb, V2, KAS, Dp, M, lng, lnb);
    stats_k<<<LPADROWS, 256, 0, stream>>>(V2, M);
    // layers 1..5: fuse LN of layer i-1 into staging (u read back from LDS
    // in the epilogue, so no global re-read / re-normalize)
    for (int i = 1; i < NLAY; i++) {
        const u16* srcb = (i & 1) ? V2 : Vb;
        u16*       dstb = (i & 1) ? Vb : V2;
        sconv_k<1><<<HD, 128, 0, stream>>>(
            srcb, dstb, KAS + (size_t)i * HD * 2 * KROW, Dp + i * HD,
            M, lng + (size_t)(i - 1) * HD, lnb + (size_t)(i - 1) * HD);
        stats_k<<<LPADROWS, 256, 0, stream>>>(dstb, M);
    }
    // P5 is in Vb; fused LN5 + final LN, in place
    lnT2_k<<<LSEQ, 512, 0, stream>>>(Vb, Vb, M, lng + 5 * HD, lnb + 5 * HD, fng, fnb);
    pool_k<<<HD, 256, 0, stream>>>(Vb, PO);
    dec_k<<<(BB * 10 + 255) / 256, 256, 0, stream>>>(PO, dw, db, out);
}

// Round 4
// 753.962 us; speedup vs baseline: 1.1419x; 1.1419x over previous
//
#include <hip/hip_runtime.h>
#include <hip/hip_bf16.h>

#define HD 512      // d_model
#define NST 64      // d_state
#define NLAY 6
#define LSEQ 784
#define BB 64       // batch
#define TOFF 800    // KAS copy0: pos t holds K[TOFF - t]; t in [17,800] real, else 0
#define LPADROWS 800  // padded L (25 tiles of 32); pad rows killed by zero-K
#define KROW 852    // u16 stride of one shifted kernel copy (4 copies per (i,h))

typedef unsigned short u16;
typedef short s8v __attribute__((ext_vector_type(8)));   // 8 bf16 (4 VGPR)
typedef float f16v __attribute__((ext_vector_type(16))); // 32x32 MFMA acc
typedef u16  u8h __attribute__((ext_vector_type(8)));    // ushort8 (16B)

// fp32 -> bf16 bits, round-to-nearest-even
__device__ __forceinline__ unsigned f2b(float f)
{
    unsigned u = __builtin_bit_cast(unsigned, f);
    return (u + 0x7FFFu + ((u >> 16) & 1u)) >> 16;
}
__device__ __forceinline__ float b2f16(u16 v)
{
    unsigned u = ((unsigned)v) << 16;
    return __builtin_bit_cast(float, u);
}
// pack 2 fp32 -> 2 bf16 (RNE), lo|hi<<16 — single HW instruction on gfx950
__device__ __forceinline__ unsigned pkbf(float lo, float hi)
{
    unsigned r;
    asm("v_cvt_pk_bf16_f32 %0, %1, %2" : "=v"(r) : "v"(lo), "v"(hi));
    return r;
}

// ---------------------------------------------------------------------------
// Per (layer,h,n): lambda = exp(dt*A), dtA, 2*Cd. Layout [i][h][n].
// ---------------------------------------------------------------------------
__global__ void precompute_k(const float* __restrict__ log_dt,
                             const float* __restrict__ log_A_real,
                             const float* __restrict__ A_imag,
                             const float* __restrict__ C_re,
                             const float* __restrict__ C_im,
                             float* __restrict__ lamr, float* __restrict__ lami,
                             float* __restrict__ dtr,  float* __restrict__ dti,
                             float* __restrict__ c2r,  float* __restrict__ c2i)
{
    int t = blockIdx.x * 256 + threadIdx.x;
    if (t >= NLAY * HD * NST) return;
    int ih = t >> 6;                       // i*HD + h
    float dt  = expf(log_dt[ih]);
    float are = -expf(log_A_real[t]);
    float aim = A_imag[t];
    float dr = are * dt, di = aim * dt;
    float er = expf(dr);
    float sn, cs; __sincosf(di, &sn, &cs);
    float lr = er * cs, li = er * sn;      // lambda
    float e1r = lr - 1.0f, e1i = li;
    float den = are * are + aim * aim;
    float qr = (e1r * are + e1i * aim) / den;
    float qi = (e1i * are - e1r * aim) / den;
    float crv = C_re[t], civ = C_im[t];
    lamr[t] = lr; lami[t] = li; dtr[t] = dr; dti[t] = di;
    c2r[t] = 2.0f * (crv * qr - civ * qi);
    c2i[t] = 2.0f * (crv * qi + civ * qr);
}

// ---------------------------------------------------------------------------
// Build KAS[i][h]: FOUR shifted copies (852 u16 each) of the reversed,
// zero-padded conv kernel.  Copy s holds K-rev at position s + t, so a read
// whose u16 index is ==0 mod 4 can pick copy (n2&3) and stay 8B-aligned.
// ---------------------------------------------------------------------------
__global__ void kq_k(const float* __restrict__ lamr, const float* __restrict__ lami,
                     const float* __restrict__ dtr,  const float* __restrict__ dti,
                     const float* __restrict__ c2r,  const float* __restrict__ c2i,
                     u16* __restrict__ KAS)
{
    int t = blockIdx.x * 256 + threadIdx.x;   // < 6*512*49
    int dc = t % 49;
    int ih = t / 49;                          // i*HD + h
    int d0 = dc * 16;
    float acc[16];
#pragma unroll
    for (int k = 0; k < 16; k++) acc[k] = 0.f;
    int base = ih * 64;
    for (int n = 0; n < 64; n++) {
        float lr = lamr[base + n], li = lami[base + n];
        float dr = dtr[base + n],  di = dti[base + n];
        float cr = c2r[base + n],  ci = c2i[base + n];
        float e = __expf(dr * (float)d0);
        float sn, cs; __sincosf(di * (float)d0, &sn, &cs);
        float pr = e * cs, pi = e * sn;       // lam^d0
#pragma unroll
        for (int k = 0; k < 16; k++) {
            acc[k] = fmaf(cr, pr, fmaf(-ci, pi, acc[k]));
            float nr = pr * lr - pi * li;
            pi = fmaf(pr, li, pi * lr);
            pr = nr;
        }
    }
    u16* rp0 = KAS + (size_t)ih * 4 * KROW;
#pragma unroll
    for (int k = 0; k < 16; k++) {
        u16 vb = (u16)f2b(acc[k]);
        int tt = TOFF - (d0 + k);
        for (int s = 0; s < 4; s++) rp0[s * KROW + s + tt] = vb;
    }
    if (dc == 0) {   // zero tails: copy s valid data at [s+17, s+800]
        for (int s = 0; s < 4; s++)
            for (int z = s + TOFF + 1; z < KROW; z++) rp0[s * KROW + z] = 0;
    }
    if (dc == 48) {
        for (int s = 0; s < 4; s++)
            for (int z = 0; z < s + 17; z++) rp0[s * KROW + z] = 0;
    }
}

// ---------------------------------------------------------------------------
// Transpose x[b][l] -> xT[l][b] (200 KB, L2-resident; cost ~2 us)
// ---------------------------------------------------------------------------
__global__ void xt_k(const float* __restrict__ x, float* __restrict__ xT)
{
    int t = blockIdx.x * 256 + threadIdx.x;   // < 784*64
    int l = t >> 6, b = t & 63;
    xT[t] = x[b * LSEQ + l];
}

// ---------------------------------------------------------------------------
// Encoder: thread = (l, h, b-oct).  Extended to LPADROWS: pad rows get ZEROS
// (so layer-0 staging never ingests uninitialized ws memory / NaNs).
// ---------------------------------------------------------------------------
__global__ void encoder_k(const float* __restrict__ xT, const float* __restrict__ ew,
                          const float* __restrict__ eb, u16* __restrict__ Vb)
{
    int g = blockIdx.x * 256 + threadIdx.x;   // < 800*512*8
    int bo = g & 7;
    int h  = (g >> 3) & 511;
    int l  = g >> 12;
    uint4* dst = (uint4*)&Vb[((size_t)l * HD + h) * BB + 8 * bo];
    if (l >= LSEQ) { *dst = (uint4){0, 0, 0, 0}; return; }
    const float4* xp = (const float4*)&xT[l * BB + 8 * bo];
    float4 a0 = xp[0], a1 = xp[1];
    float w = ew[h], bb = eb[h];
    unsigned p0 = f2b(fmaf(a0.x, w, bb)) | (f2b(fmaf(a0.y, w, bb)) << 16);
    unsigned p1 = f2b(fmaf(a0.z, w, bb)) | (f2b(fmaf(a0.w, w, bb)) << 16);
    unsigned p2 = f2b(fmaf(a1.x, w, bb)) | (f2b(fmaf(a1.y, w, bb)) << 16);
    unsigned p3 = f2b(fmaf(a1.z, w, bb)) | (f2b(fmaf(a1.w, w, bb)) << 16);
    *dst = (uint4){p0, p1, p2, p3};
}

// ---------------------------------------------------------------------------
// Per-(l,b) LayerNorm stats of pre-LN stream P: M[l][b] = {mu, rs}.
// Pad rows (l >= LSEQ) get identity stats {0,1} so fused-LN stays finite.
// ---------------------------------------------------------------------------
__global__ __launch_bounds__(256)
void stats_k(const u16* __restrict__ P, float2* __restrict__ M)
{
    __shared__ float redS[32][65], redQ[32][65];
    const int thr = threadIdx.x;
    const size_t l = blockIdx.x;
    if (l >= LSEQ) {
        if (thr < BB) M[l * BB + thr] = make_float2(0.f, 1.f);
        return;
    }
    const int bo = thr & 7;           // b = 8*bo + i
    const int ho = thr >> 3;          // h = 16*ho + k
    const u16* sp = &P[(l * HD + (size_t)ho * 16) * BB + 8 * bo];
    float s[8] = {0, 0, 0, 0, 0, 0, 0, 0};
    float q[8] = {0, 0, 0, 0, 0, 0, 0, 0};
#pragma unroll
    for (int k = 0; k < 16; k++) {
        u8h r = *(const u8h*)(sp + (size_t)k * BB);
#pragma unroll
        for (int i = 0; i < 8; i++) {
            float x = b2f16(r[i]);
            s[i] += x;
            q[i] = fmaf(x, x, q[i]);
        }
    }
#pragma unroll
    for (int i = 0; i < 8; i++) { redS[ho][8 * bo + i] = s[i]; redQ[ho][8 * bo + i] = q[i]; }
    __syncthreads();
    if (thr < 64) {
        float ts = 0.f, tq = 0.f;
#pragma unroll
        for (int g = 0; g < 32; g++) { ts += redS[g][thr]; tq += redQ[g][thr]; }
        float mu = ts * (1.0f / HD);
        float rs = rsqrtf(tq * (1.0f / HD) - mu * mu + 1e-5f);
        M[l * BB + thr] = make_float2(mu, rs);
    }
}

// ---------------------------------------------------------------------------
// STREAMING MFMA causal-Toeplitz conv, v2.  Block = (h, b-half): 1024 blocks,
// 128 thr (2 waves), 64 KB LDS -> 2 blocks/CU, 4 waves/CU (all SIMDs fed).
// The 800-row x 32-col normalized input stream lives in LDS.  A-fragments
// are consumed in BANDS of 5 deltas (afr[5][2] = 40 VGPR, next band
// prefetched) with pointer-arithmetic addressing -> structurally impossible
// to spill (register index dd is a 5-unrolled constant; g/band loops stay
// rolled).  Waves split output tiles by Ti parity.
// Per (g,band): Ti = tt + dd, t = 5*(g-band) + tt, delta = 5*band + dd.
// ---------------------------------------------------------------------------
template<int FLN>
__global__ __launch_bounds__(128, 1)
void sconv_k(const u16* __restrict__ Vb, u16* __restrict__ V2,
             const u16* __restrict__ KAS, const float* __restrict__ Dvec,
             const float2* __restrict__ M,
             const float* __restrict__ gp, const float* __restrict__ bp)
{
    __shared__ __align__(16) unsigned SB[25 * 32 * 20];   // 64,000 B

    const int thr  = threadIdx.x;
    const int h    = blockIdx.x >> 1;
    const int half = blockIdx.x & 1;
    const int lane = thr & 63;
    const int y    = __builtin_amdgcn_readfirstlane(thr >> 6);  // Ti parity
    const int n2   = lane & 31;
    const int qp   = lane >> 5;

    const float gh = FLN ? gp[h] : 0.f;
    const float bh = FLN ? bp[h] : 0.f;
    const float dcoef = 1.0f + Dvec[h];

    // A-frag base: copy sA makes (kb) a multiple of 4 u16 -> 8B-aligned loads
    const int sA = n2 & 3;
    const u16* kb = KAS + ((size_t)h * 4 + sA) * KROW + sA
                    + TOFF - n2 + 8 * qp;

    auto LOADA = [&](s8v (&A)[5][2], const u16* kpb) {
#pragma unroll
        for (int dd = 0; dd < 5; dd++)
#pragma unroll
            for (int ch = 0; ch < 2; ch++) {
                const u16* kp = kpb - 32 * dd + 16 * ch;
                union { uint2 d[2]; s8v v; } af;
                af.d[0] = *(const uint2*)__builtin_assume_aligned(kp, 8);
                af.d[1] = *(const uint2*)__builtin_assume_aligned(kp + 4, 8);
                A[dd][ch] = af.v;
            }
    };

    // ---- staging: 160 rows (5 tiles) of group g0 -> LDS, fused LN ----
    auto STAGE = [&](int g0) {
#pragma unroll
        for (int j5 = 0; j5 < 3; j5++) {
            int u = thr + 128 * j5;       // 0..319 used
            if (u < 320) {
                int rp = u >> 2;          // row-pair 0..79
                int sg = u & 3;           // 8-col seg within 32
                int r0 = 160 * g0 + 2 * rp;
                const u16* p = &Vb[((size_t)r0 * HD + h) * BB + 32 * half + 8 * sg];
                u8h ra = *(const u8h*)p;
                u8h rb = *(const u8h*)(p + (size_t)HD * BB);
                unsigned ov[8];
                if (FLN) {
                    const float4* m0 = (const float4*)&M[(size_t)r0 * BB + 32 * half + 8 * sg];
                    const float4* m1 = (const float4*)&M[(size_t)(r0 + 1) * BB + 32 * half + 8 * sg];
#pragma unroll
                    for (int i = 0; i < 4; i++) {
                        float4 ma = m0[i], mb = m1[i];   // (mu,rs,mu,rs)
                        float A0 = ma.y * gh, C0 = fmaf(-ma.x, A0, bh);
                        float A1 = ma.w * gh, C1 = fmaf(-ma.z, A1, bh);
                        float B0 = mb.y * gh, D0 = fmaf(-mb.x, B0, bh);
                        float B1 = mb.w * gh, D1 = fmaf(-mb.z, B1, bh);
                        float x0 = fmaf(b2f16(ra[2 * i]),     A0, C0);
                        float x1 = fmaf(b2f16(ra[2 * i + 1]), A1, C1);
                        float y0 = fmaf(b2f16(rb[2 * i]),     B0, D0);
                        float y1 = fmaf(b2f16(rb[2 * i + 1]), B1, D1);
                        ov[2 * i]     = pkbf(x0, y0);
                        ov[2 * i + 1] = pkbf(x1, y1);
                    }
                } else {
#pragma unroll
                    for (int i = 0; i < 8; i++)
                        ov[i] = (unsigned)ra[i] | ((unsigned)rb[i] << 16);
                }
                int tt = 5 * g0 + (rp >> 4);
                int jj = rp & 15;
                unsigned* dst = &SB[(tt * 32 + 8 * sg) * 20 + (jj ^ ((sg & 3) << 2))];
#pragma unroll
                for (int k = 0; k < 8; k++) dst[k * 20] = ov[k];
            }
        }
    };

    const int swz = ((n2 >> 3) & 3) << 2;
    const unsigned* bb0 = &SB[n2 * 20 + ((4 * qp) ^ swz)];
    const unsigned* bb1 = &SB[n2 * 20 + ((8 + 4 * qp) ^ swz)];

    STAGE(0);
    __syncthreads();

    for (int g = 0; g < 5; g++) {
        f16v acc[3];
#pragma unroll
        for (int i = 0; i < 3; i++)
#pragma unroll
            for (int r = 0; r < 16; r++) acc[i][r] = 0.f;

        s8v afr[5][2], afn[5][2];
        LOADA(afr, kb);
        for (int band = 0; band <= g; band++) {
            if (band < g) LOADA(afn, kb - 160 * (band + 1));
            const int tbase = 5 * (g - band);
#pragma unroll
            for (int tti = 0; tti < 9; tti++) {
                const int tt = tti - 4;
                int t = tbase + tt;
                int tc = t < 0 ? 0 : t;               // clamp: read always safe
                const unsigned* bp0 = bb0 + tc * 640;
                const unsigned* bp1 = bb1 + tc * 640;
                s8v bv0 = *(const s8v*)__builtin_assume_aligned(bp0, 16);
                s8v bv1 = *(const s8v*)__builtin_assume_aligned(bp1, 16);
                if (t >= 0) {                          // wave-uniform
#pragma unroll
                    for (int ch = 0; ch < 2; ch++)
#pragma unroll
                        for (int dd = 0; dd < 5; dd++) {
                            const int Ti = tt + dd;
                            if (Ti >= 0 && Ti <= 4) {
                                if ((Ti & 1) == y)    // scalar (y in SGPR)
                                    acc[Ti >> 1] = __builtin_amdgcn_mfma_f32_32x32x16_bf16(
                                        afr[dd][ch], ch ? bv1 : bv0, acc[Ti >> 1], 0, 0, 0);
                            }
                        }
                }
            }
            if (band < g) {
#pragma unroll
                for (int dd = 0; dd < 5; dd++) {
                    afr[dd][0] = afn[dd][0];
                    afr[dd][1] = afn[dd][1];
                }
            }
        }

        // ---- epilogue: V2 = bf16(y + (1+D)*u), u re-read from LDS ----
#pragma unroll
        for (int q = 0; q < 3; q++) {
            const int Ti = 2 * q + y;                 // wave-uniform
            if (Ti <= 4) {
                const int T = 5 * g + Ti;
#pragma unroll
                for (int k = 0; k < 4; k++) {
                    const int jjE = (2 * qp + 4 * k) ^ swz;
                    const uint2 dw = *(const uint2*)__builtin_assume_aligned(
                        &SB[(T * 32 + n2) * 20 + jjE], 8);
                    float u0 = b2f16((u16)(dw.x & 0xffff));
                    float u1 = b2f16((u16)(dw.x >> 16));
                    float u2 = b2f16((u16)(dw.y & 0xffff));
                    float u3 = b2f16((u16)(dw.y >> 16));
                    const int l = 32 * T + 8 * k + 4 * qp;
                    size_t a = ((size_t)l * HD + h) * BB + 32 * half + n2;
                    V2[a]                       = (u16)f2b(fmaf(dcoef, u0, acc[q][4 * k + 0]));
                    V2[a + (size_t)HD * BB]     = (u16)f2b(fmaf(dcoef, u1, acc[q][4 * k + 1]));
                    V2[a + (size_t)2 * HD * BB] = (u16)f2b(fmaf(dcoef, u2, acc[q][4 * k + 2]));
                    V2[a + (size_t)3 * HD * BB] = (u16)f2b(fmaf(dcoef, u3, acc[q][4 * k + 3]));
                }
            }
        }

        if (g < 4) STAGE(g + 1);
        __syncthreads();
    }
}

// ---------------------------------------------------------------------------
// Fused double-LN tail: u6 = LN5(P5) (per-(l,b) stats in M, per-h g5/b5),
// then final LN over h of u6, write bf16. In-place safe (block owns its l).
// ---------------------------------------------------------------------------
__global__ __launch_bounds__(512)
void lnT2_k(const u16* __restrict__ src, u16* __restrict__ dst,
            const float2* __restrict__ M,
            const float* __restrict__ g5p, const float* __restrict__ b5p,
            const float* __restrict__ gp, const float* __restrict__ bp)
{
    __shared__ float redS[64][65], redQ[64][65];
    __shared__ float mus[64], rss[64];
    __shared__ float gs[512], bs[512];
    const int thr = threadIdx.x;
    const int bo = thr & 7;           // b = 8*bo + i
    const int hg = thr >> 3;          // h = 8*hg + k
    const size_t l = blockIdx.x;
    gs[thr] = gp[thr]; bs[thr] = bp[thr];

    const float4* mp = (const float4*)&M[l * BB + 8 * bo];
    float4 m0 = mp[0], m1 = mp[1], m2 = mp[2], m3 = mp[3];
    float mu5[8] = {m0.x, m0.z, m1.x, m1.z, m2.x, m2.z, m3.x, m3.z};
    float rs5[8] = {m0.y, m0.w, m1.y, m1.w, m2.y, m2.w, m3.y, m3.w};

    const u16* sp = &src[(l * HD + (size_t)hg * 8) * BB + 8 * bo];
    float v[64];                       // v[k*8+i]
    float s[8] = {0, 0, 0, 0, 0, 0, 0, 0};
    float q[8] = {0, 0, 0, 0, 0, 0, 0, 0};
#pragma unroll
    for (int k = 0; k < 8; k++) {
        u8h r = *(const u8h*)(sp + (size_t)k * BB);
        float g5 = g5p[hg * 8 + k], b5 = b5p[hg * 8 + k];
#pragma unroll
        for (int i = 0; i < 8; i++) {
            float x = fmaf(b2f16(r[i]) - mu5[i], rs5[i] * g5, b5);
            v[k * 8 + i] = x;
            s[i] += x;
            q[i] = fmaf(x, x, q[i]);
        }
    }
#pragma unroll
    for (int i = 0; i < 8; i++) { redS[hg][8 * bo + i] = s[i]; redQ[hg][8 * bo + i] = q[i]; }
    __syncthreads();
    if (thr < 64) {
        float ts = 0.f, tq = 0.f;
#pragma unroll
        for (int g = 0; g < 64; g++) { ts += redS[g][thr]; tq += redQ[g][thr]; }
        float mu = ts * (1.0f / HD);
        mus[thr] = mu;
        rss[thr] = rsqrtf(tq * (1.0f / HD) - mu * mu + 1e-5f);
    }
    __syncthreads();
    float mu[8], rs[8];
#pragma unroll
    for (int i = 0; i < 8; i++) { mu[i] = mus[8 * bo + i]; rs[i] = rss[8 * bo + i]; }
    u16* dp = &dst[(l * HD + (size_t)hg * 8) * BB + 8 * bo];
#pragma unroll
    for (int k = 0; k < 8; k++) {
        float g = gs[hg * 8 + k], bb = bs[hg * 8 + k];
        u8h wv;
#pragma unroll
        for (int i = 0; i < 8; i++)
            wv[i] = (u16)f2b(fmaf((v[k * 8 + i] - mu[i]) * rs[i], g, bb));
        *(u8h*)(dp + (size_t)k * BB) = wv;
    }
}

// ---------------------------------------------------------------------------
// Mean-pool over l from bf16 Vb: PO[h*64+b] = mean_l Vb[l][h][b].
// ---------------------------------------------------------------------------
__global__ void pool_k(const u16* __restrict__ Vb, float* __restrict__ PO)
{
    __shared__ float red[4][64];
    int h = blockIdx.x;
    int b = threadIdx.x & 63;
    int lg = threadIdx.x >> 6;               // 0..3
    const u16* p = &Vb[(size_t)h * BB + b];
    float s = 0.f;
    for (int l = lg; l < LSEQ; l += 4) s += b2f16(p[(size_t)l * HD * BB]);
    red[lg][b] = s;
    __syncthreads();
    if (threadIdx.x < 64) {
        float t = red[0][b] + red[1][b] + red[2][b] + red[3][b];
        PO[h * BB + b] = t * (1.0f / LSEQ);
    }
}

// ---------------------------------------------------------------------------
// Decoder: out[b,c] = PO[:,b] . dec_w[:,c] + dec_b[c]
// ---------------------------------------------------------------------------
__global__ void dec_k(const float* __restrict__ PO, const float* __restrict__ w,
                      const float* __restrict__ bias, float* __restrict__ out)
{
    int t = blockIdx.x * 256 + threadIdx.x;
    if (t >= BB * 10) return;
    int cc = t % 10, b = t / 10;
    float acc = bias[cc];
    for (int hh = 0; hh < HD; hh++)
        acc = fmaf(PO[hh * BB + b], w[hh * 10 + cc], acc);
    out[t] = acc;
}

// ---------------------------------------------------------------------------
extern "C" void kernel_launch(void* const* d_in, const int* in_sizes, int n_in,
                              void* d_out, int out_size, void* d_ws, size_t ws_size,
                              hipStream_t stream)
{
    const float* x   = (const float*)d_in[0];
    const float* ew  = (const float*)d_in[1];
    const float* eb  = (const float*)d_in[2];
    const float* ldt = (const float*)d_in[3];
    const float* lar = (const float*)d_in[4];
    const float* aim = (const float*)d_in[5];
    const float* cre = (const float*)d_in[6];
    const float* cim = (const float*)d_in[7];
    const float* Dp  = (const float*)d_in[8];
    const float* lng = (const float*)d_in[9];
    const float* lnb = (const float*)d_in[10];
    const float* fng = (const float*)d_in[11];
    const float* fnb = (const float*)d_in[12];
    const float* dw  = (const float*)d_in[13];
    const float* db  = (const float*)d_in[14];
    float* out = (float*)d_out;

    const size_t SZB = (size_t)BB * LPADROWS * HD;   // 26,214,400 u16 slots
    const size_t PP  = (size_t)NLAY * HD * NST;      // 196,608
    u16*   Vb  = (u16*)d_ws;                // bf16 stream buffer A [l][h][b]
    u16*   V2  = Vb + SZB;                  // bf16 stream buffer B
    float* PAR = (float*)(V2 + SZB);
    float* lamr = PAR,        * lami = PAR + PP;
    float* dtr  = PAR + 2*PP, * dti  = PAR + 3*PP;
    float* c2r  = PAR + 4*PP, * c2i  = PAR + 5*PP;
    u16* KAS = (u16*)(PAR + 6 * PP);                 // 6*512*4*852 u16 = 20.9 MB
    float* PO = (float*)(KAS + (size_t)NLAY * HD * 4 * KROW);
    float* xT = PO + BB * HD;                        // 784*64 fp32
    // M (LN stats, 800*64 float2 = 400KB) aliases PAR: PAR only feeds kq_k,
    // which completes before the first stats_k writes M.
    float2* M = (float2*)PAR;
    // total ~131 MB

    precompute_k<<<(NLAY * HD * NST + 255) / 256, 256, 0, stream>>>(
        ldt, lar, aim, cre, cim, lamr, lami, dtr, dti, c2r, c2i);
    kq_k<<<(NLAY * HD * 49) / 256, 256, 0, stream>>>(
        lamr, lami, dtr, dti, c2r, c2i, KAS);
    xt_k<<<(LSEQ * BB) / 256, 256, 0, stream>>>(x, xT);
    encoder_k<<<(LPADROWS * HD * 8) / 256, 256, 0, stream>>>(xT, ew, eb, Vb);

    // layer 0: raw input (no fused LN), P0 -> V2
    sconv_k<0><<<HD * 2, 128, 0, stream>>>(Vb, V2, KAS, Dp, M, lng, lnb);
    stats_k<<<LPADROWS, 256, 0, stream>>>(V2, M);
    // layers 1..5: fuse LN of layer i-1 into staging (u read back from LDS
    // in the epilogue, so no global re-read / re-normalize)
    for (int i = 1; i < NLAY; i++) {
        const u16* srcb = (i & 1) ? V2 : Vb;
        u16*       dstb = (i & 1) ? Vb : V2;
        sconv_k<1><<<HD * 2, 128, 0, stream>>>(
            srcb, dstb, KAS + (size_t)i * HD * 4 * KROW, Dp + i * HD,
            M, lng + (size_t)(i - 1) * HD, lnb + (size_t)(i - 1) * HD);
        stats_k<<<LPADROWS, 256, 0, stream>>>(dstb, M);
    }
    // P5 is in Vb; fused LN5 + final LN, in place
    lnT2_k<<<LSEQ, 512, 0, stream>>>(Vb, Vb, M, lng + 5 * HD, lnb + 5 * HD, fng, fnb);
    pool_k<<<HD, 256, 0, stream>>>(Vb, PO);
    dec_k<<<(BB * 10 + 255) / 256, 256, 0, stream>>>(PO, dw, db, out);
}